// Round 12
// baseline (178.342 us; speedup 1.0000x reference)
//
#include <hip/hip_runtime.h>
#include <hip/hip_fp16.h>

// out[b, m, r] = x[b, ind[r,m]] * filters[r, ind[r,m]]
// rem = m*512+r; out flat = b*65536 + rem. Index table fixed across rows.
//
// map11 = map10 (sorted-gather, LDS-scatter) at HALF-ROW granularity:
// entries counting-sorted by key2 = (rem>>15)*65536 + idx. Block g handles
// row g>>1, half g&1: stream its sorted 32768-entry table, gather x from
// global fp32 (quasi-sequential), scatter fp16 product into 64KB LDS outbuf,
// one barrier, coalesced sweep. 64KB LDS + <=64 VGPR -> 2 blocks/CU
// (32 waves) vs map10's 1 (16) -- the ~150us plateau tracked occupancy.

constexpr int D_ROW = 128;
constexpr int D_COL = 512;
constexpr int D_ALL = D_ROW * D_COL;   // 65536
constexpr int BATCH = 1024;
constexpr int HALF  = 32768;
constexpr int NBIN  = 2 * D_ALL;       // 131072 bins

__device__ __forceinline__ void lds_barrier() {
    asm volatile("s_waitcnt lgkmcnt(0)" ::: "memory");
    __builtin_amdgcn_s_barrier();
}

// ---------------- build: counting sort by (half, idx) ----------------
// ws: offs u32[131072] | part u32[128] (+pad) | idx_rem u32[65536] | w16 u16[65536]

__global__ void __launch_bounds__(1024)
k_zero(unsigned* __restrict__ offs) {
    offs[blockIdx.x * 1024 + threadIdx.x] = 0u;
}

__global__ void __launch_bounds__(1024)
k_hist(const int* __restrict__ ind, unsigned* __restrict__ offs) {
    const int rem = blockIdx.x * 1024 + threadIdx.x;    // 0..65535
    const int m = rem >> 9, r = rem & 511;
    const int idx = ind[r * D_ROW + m];
    const unsigned key2 = ((unsigned)(rem >> 15) << 16) | (unsigned)idx;
    atomicAdd(&offs[key2], 1u);
}

// Exclusive scan of each 1024-bin group in place; group totals -> part.
__global__ void __launch_bounds__(1024)
k_scan1(unsigned* __restrict__ offs, unsigned* __restrict__ part) {
    __shared__ unsigned s[1024];
    const int t = threadIdx.x;
    const int g = blockIdx.x * 1024 + t;
    const unsigned v = offs[g];
    s[t] = v;
    __syncthreads();
    #pragma unroll
    for (int d = 1; d < 1024; d <<= 1) {
        unsigned a = (t >= d) ? s[t - d] : 0u;
        __syncthreads();
        s[t] += a;
        __syncthreads();
    }
    offs[g] = s[t] - v;                      // exclusive prefix within group
    if (t == 1023) part[blockIdx.x] = s[t];  // group total
}

// Exclusive scan of the 128 group totals.
__global__ void __launch_bounds__(128)
k_scan2(unsigned* __restrict__ part) {
    __shared__ unsigned s[128];
    const int t = threadIdx.x;
    const unsigned v = part[t];
    s[t] = v;
    __syncthreads();
    #pragma unroll
    for (int d = 1; d < 128; d <<= 1) {
        unsigned a = (t >= d) ? s[t - d] : 0u;
        __syncthreads();
        s[t] += a;
        __syncthreads();
    }
    part[t] = s[t] - v;
}

__global__ void __launch_bounds__(1024)
k_scatter(const float* __restrict__ filters,
          const int*   __restrict__ ind,
          unsigned* __restrict__ offs,
          const unsigned* __restrict__ part,
          unsigned* __restrict__ idx_rem,
          unsigned short* __restrict__ wbuf) {
    const int rem = blockIdx.x * 1024 + threadIdx.x;    // 0..65535
    const int m = rem >> 9, r = rem & 511;
    const int idx = ind[r * D_ROW + m];
    const float w = filters[(size_t)r * D_ALL + idx];
    const unsigned key2 = ((unsigned)(rem >> 15) << 16) | (unsigned)idx;
    const unsigned pos = part[key2 >> 10] + atomicAdd(&offs[key2], 1u);
    idx_rem[pos] = ((unsigned)idx << 16) | (unsigned)rem;
    wbuf[pos]    = __half_as_ushort(__float2half_rn(w));
}

// ---------------- main ----------------
__global__ void __launch_bounds__(1024)
map11(const float* __restrict__ x,
      const uint4* __restrict__ ir4,       // 4 packed (idx<<16|rem) per load
      const ushort4* __restrict__ w4a,     // 4 fp16 w per load
      float* __restrict__ out) {
    __shared__ __half outbuf[HALF];        // 64 KB -> 2 blocks/CU
    const int t = threadIdx.x;             // 0..1023
    const unsigned g = blockIdx.x;         // 0..2047
    const unsigned b = g >> 1, h = g & 1u;
    const float* xb = x + ((size_t)b << 16);

    const uint4*   irp = ir4 + h * (HALF / 4);
    const ushort4* wp  = w4a + h * (HALF / 4);

    // 32 sorted entries/thread; gather window per wave ~1KB of x (L1 lines
    // fully consumed). Table loads independent of gathers; unroll-4 keeps
    // ~16 gathers in flight without blowing the 64-VGPR budget.
    #pragma unroll 4
    for (int e = 0; e < 8; ++e) {
        const uint4   ir = irp[e * 1024 + t];
        const ushort4 w4 = wp [e * 1024 + t];
        const float f0 = xb[ir.x >> 16];
        const float f1 = xb[ir.y >> 16];
        const float f2 = xb[ir.z >> 16];
        const float f3 = xb[ir.w >> 16];
        outbuf[ir.x & 32767u] = __float2half_rn(
            f0 * __half2float(__ushort_as_half(w4.x)));
        outbuf[ir.y & 32767u] = __float2half_rn(
            f1 * __half2float(__ushort_as_half(w4.y)));
        outbuf[ir.z & 32767u] = __float2half_rn(
            f2 * __half2float(__ushort_as_half(w4.z)));
        outbuf[ir.w & 32767u] = __float2half_rn(
            f3 * __half2float(__ushort_as_half(w4.w)));
    }
    lds_barrier();   // rem covers the half exactly once -> outbuf full

    // Sweep: fp16 outbuf -> fp32 out, fully coalesced.
    float* ob = out + ((size_t)b << 16) + h * HALF;
    #pragma unroll
    for (int i = 0; i < 4; ++i) {
        uint4 u = *reinterpret_cast<const uint4*>(&outbuf[i * 8192 + t * 8]);
        __half2 a = *reinterpret_cast<__half2*>(&u.x);
        __half2 bb = *reinterpret_cast<__half2*>(&u.y);
        __half2 c = *reinterpret_cast<__half2*>(&u.z);
        __half2 d = *reinterpret_cast<__half2*>(&u.w);
        float4 f0, f1;
        f0.x = __half2float(a.x);  f0.y = __half2float(a.y);
        f0.z = __half2float(bb.x); f0.w = __half2float(bb.y);
        f1.x = __half2float(c.x);  f1.y = __half2float(c.y);
        f1.z = __half2float(d.x);  f1.w = __half2float(d.y);
        *reinterpret_cast<float4*>(ob + i * 8192 + t * 8)     = f0;
        *reinterpret_cast<float4*>(ob + i * 8192 + t * 8 + 4) = f1;
    }
}

// ---------------- fallbacks (map8 = 148us known-good) ----------------
__global__ void __launch_bounds__(256)
build_pk(const float* __restrict__ filters,
         const int*   __restrict__ ind,
         unsigned* __restrict__ pk) {
    int t = blockIdx.x * 256 + threadIdx.x;
    if (t >= D_ALL) return;
    int m = t >> 9, r = t & 511;
    int idx = ind[r * D_ROW + m];
    __half hw = __float2half_rn(filters[(size_t)r * D_ALL + idx]);
    pk[t] = ((unsigned)__half_as_ushort(hw) << 16) | (unsigned)idx;
}

__device__ __forceinline__ float map_one(const __half* xs, unsigned p) {
    return __half2float(xs[p & 0xffffu]) *
           __half2float(__ushort_as_half((unsigned short)(p >> 16)));
}
__device__ __forceinline__ unsigned h2bits(float a, float b) {
    __half2 h = __floats2half2_rn(a, b);
    return *reinterpret_cast<unsigned*>(&h);
}

__global__ void __launch_bounds__(1024, 4)
map8(const float* __restrict__ x, const uint4* __restrict__ pk4,
     float* __restrict__ out) {
    __shared__ __half xs[D_ALL];
    const int t = threadIdx.x;
    const int row0 = blockIdx.x * 4;
    float4 buf[16];
    {
        const float4* src = reinterpret_cast<const float4*>(x + ((size_t)row0 << 16));
        #pragma unroll
        for (int i = 0; i < 8; ++i) {
            buf[2 * i]     = src[i * 2048 + t * 2];
            buf[2 * i + 1] = src[i * 2048 + t * 2 + 1];
        }
    }
    #pragma unroll
    for (int k = 0; k < 4; ++k) {
        #pragma unroll
        for (int i = 0; i < 8; ++i) {
            uint4 u;
            u.x = h2bits(buf[2 * i].x,     buf[2 * i].y);
            u.y = h2bits(buf[2 * i].z,     buf[2 * i].w);
            u.z = h2bits(buf[2 * i + 1].x, buf[2 * i + 1].y);
            u.w = h2bits(buf[2 * i + 1].z, buf[2 * i + 1].w);
            *reinterpret_cast<uint4*>(xs + (size_t)(i * 2048 + t * 2) * 4) = u;
        }
        lds_barrier();
        float* ob = out + ((size_t)(row0 + k) << 16);
        #pragma unroll 4
        for (int j = 0; j < 16; ++j) {
            uint4 p = pk4[j * 1024 + t];
            float4 r;
            r.x = map_one(xs, p.x); r.y = map_one(xs, p.y);
            r.z = map_one(xs, p.z); r.w = map_one(xs, p.w);
            *reinterpret_cast<float4*>(ob + j * 4096 + t * 4) = r;
        }
        __builtin_amdgcn_sched_barrier(0);
        if (k + 1 < 4) {
            const float4* src = reinterpret_cast<const float4*>(
                x + ((size_t)(row0 + k + 1) << 16));
            #pragma unroll
            for (int i = 0; i < 8; ++i) {
                buf[2 * i]     = src[i * 2048 + t * 2];
                buf[2 * i + 1] = src[i * 2048 + t * 2 + 1];
            }
        }
        __builtin_amdgcn_sched_barrier(0);
        lds_barrier();
    }
}

__global__ void __launch_bounds__(256)
map_kernel_nows(const float* __restrict__ x,
                const float* __restrict__ filters,
                const int*   __restrict__ ind,
                float*       __restrict__ out) {
    size_t o = (size_t)blockIdx.x * 256 + threadIdx.x;
    if (o >= (size_t)BATCH * D_ALL) return;
    unsigned b = (unsigned)(o >> 16);
    unsigned rem = (unsigned)(o & 65535u);
    unsigned m = rem >> 9, r = rem & 511u;
    int idx = ind[r * D_ROW + m];
    out[o] = x[((size_t)b << 16) + idx] * filters[(size_t)r * D_ALL + idx];
}

extern "C" void kernel_launch(void* const* d_in, const int* in_sizes, int n_in,
                              void* d_out, int out_size, void* d_ws, size_t ws_size,
                              hipStream_t stream) {
    const float* x       = (const float*)d_in[0];
    const float* filters = (const float*)d_in[1];
    const int*   ind     = (const int*)d_in[2];
    float*       out     = (float*)d_out;

    // ws layout for map11
    const size_t off_offs = 0;                               // u32[131072]
    const size_t off_part = off_offs + (size_t)NBIN * 4;     // u32[128] (+pad to 512)
    const size_t off_ir   = off_part + 512;                  // u32[65536]
    const size_t off_w    = off_ir + (size_t)D_ALL * 4;      // u16[65536]
    const size_t need11   = off_w + (size_t)D_ALL * 2;       // ~1.0 MB
    const size_t need8    = (size_t)D_ALL * sizeof(unsigned);

    if (ws_size >= need11) {
        unsigned* offs = (unsigned*)((char*)d_ws + off_offs);
        unsigned* part = (unsigned*)((char*)d_ws + off_part);
        unsigned* irb  = (unsigned*)((char*)d_ws + off_ir);
        unsigned short* wbuf = (unsigned short*)((char*)d_ws + off_w);
        k_zero   <<<NBIN / 1024, 1024, 0, stream>>>(offs);
        k_hist   <<<D_ALL / 1024, 1024, 0, stream>>>(ind, offs);
        k_scan1  <<<NBIN / 1024, 1024, 0, stream>>>(offs, part);
        k_scan2  <<<1, 128, 0, stream>>>(part);
        k_scatter<<<D_ALL / 1024, 1024, 0, stream>>>(filters, ind, offs, part, irb, wbuf);
        map11<<<2 * BATCH, 1024, 0, stream>>>(
            x, reinterpret_cast<const uint4*>(irb),
            reinterpret_cast<const ushort4*>(wbuf), out);
    } else if (ws_size >= need8) {
        unsigned* pk = (unsigned*)d_ws;
        build_pk<<<D_ALL / 256, 256, 0, stream>>>(filters, ind, pk);
        map8<<<BATCH / 4, 1024, 0, stream>>>(
            x, reinterpret_cast<const uint4*>(pk), out);
    } else {
        map_kernel_nows<<<(BATCH * (size_t)D_ALL) / 256, 256, 0, stream>>>(
            x, filters, ind, out);
    }
}

// Round 13
// 165.555 us; speedup vs baseline: 1.0772x; 1.0772x over previous
//
#include <hip/hip_runtime.h>
#include <hip/hip_fp16.h>

// out[b, m, r] = x[b, ind[r,m]] * filters[r, ind[r,m]]
// rem = m*512+r; out flat = b*65536 + rem. Index table fixed across rows.
//
// map12 = map11 (sorted-gather half-rows, 64KB LDS outbuf, 2 blocks/CU)
// with an XCD-pairing swizzle: b = (g>>4)*8 + (g&7), h = (g>>3)&1.
// Row b's two half-blocks are 8 apart in blockIdx -> same XCD (g%8 equal),
// dispatched near-simultaneously -> the second half's full-row gather hits
// the XCD L2 instead of re-fetching HBM (map11's FETCH was 2x for this).

constexpr int D_ROW = 128;
constexpr int D_COL = 512;
constexpr int D_ALL = D_ROW * D_COL;   // 65536
constexpr int BATCH = 1024;
constexpr int HALF  = 32768;
constexpr int NBIN  = 2 * D_ALL;       // 131072 bins

__device__ __forceinline__ void lds_barrier() {
    asm volatile("s_waitcnt lgkmcnt(0)" ::: "memory");
    __builtin_amdgcn_s_barrier();
}

// ---------------- build: counting sort by (half, idx) ----------------
// ws: offs u32[131072] | part u32[128] (+pad) | idx_rem u32[65536] | w16 u16[65536]

__global__ void __launch_bounds__(1024)
k_zero(unsigned* __restrict__ offs) {
    offs[blockIdx.x * 1024 + threadIdx.x] = 0u;
}

__global__ void __launch_bounds__(1024)
k_hist(const int* __restrict__ ind, unsigned* __restrict__ offs) {
    const int rem = blockIdx.x * 1024 + threadIdx.x;    // 0..65535
    const int m = rem >> 9, r = rem & 511;
    const int idx = ind[r * D_ROW + m];
    const unsigned key2 = ((unsigned)(rem >> 15) << 16) | (unsigned)idx;
    atomicAdd(&offs[key2], 1u);
}

// Exclusive scan of each 1024-bin group in place; group totals -> part.
__global__ void __launch_bounds__(1024)
k_scan1(unsigned* __restrict__ offs, unsigned* __restrict__ part) {
    __shared__ unsigned s[1024];
    const int t = threadIdx.x;
    const int g = blockIdx.x * 1024 + t;
    const unsigned v = offs[g];
    s[t] = v;
    __syncthreads();
    #pragma unroll
    for (int d = 1; d < 1024; d <<= 1) {
        unsigned a = (t >= d) ? s[t - d] : 0u;
        __syncthreads();
        s[t] += a;
        __syncthreads();
    }
    offs[g] = s[t] - v;                      // exclusive prefix within group
    if (t == 1023) part[blockIdx.x] = s[t];  // group total
}

// Exclusive scan of the 128 group totals.
__global__ void __launch_bounds__(128)
k_scan2(unsigned* __restrict__ part) {
    __shared__ unsigned s[128];
    const int t = threadIdx.x;
    const unsigned v = part[t];
    s[t] = v;
    __syncthreads();
    #pragma unroll
    for (int d = 1; d < 128; d <<= 1) {
        unsigned a = (t >= d) ? s[t - d] : 0u;
        __syncthreads();
        s[t] += a;
        __syncthreads();
    }
    part[t] = s[t] - v;
}

__global__ void __launch_bounds__(1024)
k_scatter(const float* __restrict__ filters,
          const int*   __restrict__ ind,
          unsigned* __restrict__ offs,
          const unsigned* __restrict__ part,
          unsigned* __restrict__ idx_rem,
          unsigned short* __restrict__ wbuf) {
    const int rem = blockIdx.x * 1024 + threadIdx.x;    // 0..65535
    const int m = rem >> 9, r = rem & 511;
    const int idx = ind[r * D_ROW + m];
    const float w = filters[(size_t)r * D_ALL + idx];
    const unsigned key2 = ((unsigned)(rem >> 15) << 16) | (unsigned)idx;
    const unsigned pos = part[key2 >> 10] + atomicAdd(&offs[key2], 1u);
    idx_rem[pos] = ((unsigned)idx << 16) | (unsigned)rem;
    wbuf[pos]    = __half_as_ushort(__float2half_rn(w));
}

// ---------------- main ----------------
__global__ void __launch_bounds__(1024)
map12(const float* __restrict__ x,
      const uint4* __restrict__ ir4,       // 4 packed (idx<<16|rem) per load
      const ushort4* __restrict__ w4a,     // 4 fp16 w per load
      float* __restrict__ out) {
    __shared__ __half outbuf[HALF];        // 64 KB -> 2 blocks/CU
    const int t = threadIdx.x;             // 0..1023
    const unsigned g = blockIdx.x;         // 0..2047
    // XCD-pairing swizzle: halves of a row are 8 apart (same XCD), adjacent
    // in dispatch time -> second half's row gather L2-hits.
    const unsigned b = ((g >> 4) << 3) | (g & 7u);
    const unsigned h = (g >> 3) & 1u;
    const float* xb = x + ((size_t)b << 16);

    const uint4*   irp = ir4 + h * (HALF / 4);
    const ushort4* wp  = w4a + h * (HALF / 4);

    // 32 sorted entries/thread; quasi-sequential gather (sorted idx).
    #pragma unroll 4
    for (int e = 0; e < 8; ++e) {
        const uint4   ir = irp[e * 1024 + t];
        const ushort4 w4 = wp [e * 1024 + t];
        const float f0 = xb[ir.x >> 16];
        const float f1 = xb[ir.y >> 16];
        const float f2 = xb[ir.z >> 16];
        const float f3 = xb[ir.w >> 16];
        outbuf[ir.x & 32767u] = __float2half_rn(
            f0 * __half2float(__ushort_as_half(w4.x)));
        outbuf[ir.y & 32767u] = __float2half_rn(
            f1 * __half2float(__ushort_as_half(w4.y)));
        outbuf[ir.z & 32767u] = __float2half_rn(
            f2 * __half2float(__ushort_as_half(w4.z)));
        outbuf[ir.w & 32767u] = __float2half_rn(
            f3 * __half2float(__ushort_as_half(w4.w)));
    }
    lds_barrier();   // rem covers the half exactly once -> outbuf full

    // Sweep: fp16 outbuf -> fp32 out, fully coalesced.
    float* ob = out + ((size_t)b << 16) + h * HALF;
    #pragma unroll
    for (int i = 0; i < 4; ++i) {
        uint4 u = *reinterpret_cast<const uint4*>(&outbuf[i * 8192 + t * 8]);
        __half2 a = *reinterpret_cast<__half2*>(&u.x);
        __half2 bb = *reinterpret_cast<__half2*>(&u.y);
        __half2 c = *reinterpret_cast<__half2*>(&u.z);
        __half2 d = *reinterpret_cast<__half2*>(&u.w);
        float4 f0, f1;
        f0.x = __half2float(a.x);  f0.y = __half2float(a.y);
        f0.z = __half2float(bb.x); f0.w = __half2float(bb.y);
        f1.x = __half2float(c.x);  f1.y = __half2float(c.y);
        f1.z = __half2float(d.x);  f1.w = __half2float(d.y);
        *reinterpret_cast<float4*>(ob + i * 8192 + t * 8)     = f0;
        *reinterpret_cast<float4*>(ob + i * 8192 + t * 8 + 4) = f1;
    }
}

// ---------------- fallbacks (map8 = 148us known-good) ----------------
__global__ void __launch_bounds__(256)
build_pk(const float* __restrict__ filters,
         const int*   __restrict__ ind,
         unsigned* __restrict__ pk) {
    int t = blockIdx.x * 256 + threadIdx.x;
    if (t >= D_ALL) return;
    int m = t >> 9, r = t & 511;
    int idx = ind[r * D_ROW + m];
    __half hw = __float2half_rn(filters[(size_t)r * D_ALL + idx]);
    pk[t] = ((unsigned)__half_as_ushort(hw) << 16) | (unsigned)idx;
}

__device__ __forceinline__ float map_one(const __half* xs, unsigned p) {
    return __half2float(xs[p & 0xffffu]) *
           __half2float(__ushort_as_half((unsigned short)(p >> 16)));
}
__device__ __forceinline__ unsigned h2bits(float a, float b) {
    __half2 h = __floats2half2_rn(a, b);
    return *reinterpret_cast<unsigned*>(&h);
}

__global__ void __launch_bounds__(1024, 4)
map8(const float* __restrict__ x, const uint4* __restrict__ pk4,
     float* __restrict__ out) {
    __shared__ __half xs[D_ALL];
    const int t = threadIdx.x;
    const int row0 = blockIdx.x * 4;
    float4 buf[16];
    {
        const float4* src = reinterpret_cast<const float4*>(x + ((size_t)row0 << 16));
        #pragma unroll
        for (int i = 0; i < 8; ++i) {
            buf[2 * i]     = src[i * 2048 + t * 2];
            buf[2 * i + 1] = src[i * 2048 + t * 2 + 1];
        }
    }
    #pragma unroll
    for (int k = 0; k < 4; ++k) {
        #pragma unroll
        for (int i = 0; i < 8; ++i) {
            uint4 u;
            u.x = h2bits(buf[2 * i].x,     buf[2 * i].y);
            u.y = h2bits(buf[2 * i].z,     buf[2 * i].w);
            u.z = h2bits(buf[2 * i + 1].x, buf[2 * i + 1].y);
            u.w = h2bits(buf[2 * i + 1].z, buf[2 * i + 1].w);
            *reinterpret_cast<uint4*>(xs + (size_t)(i * 2048 + t * 2) * 4) = u;
        }
        lds_barrier();
        float* ob = out + ((size_t)(row0 + k) << 16);
        #pragma unroll 4
        for (int j = 0; j < 16; ++j) {
            uint4 p = pk4[j * 1024 + t];
            float4 r;
            r.x = map_one(xs, p.x); r.y = map_one(xs, p.y);
            r.z = map_one(xs, p.z); r.w = map_one(xs, p.w);
            *reinterpret_cast<float4*>(ob + j * 4096 + t * 4) = r;
        }
        __builtin_amdgcn_sched_barrier(0);
        if (k + 1 < 4) {
            const float4* src = reinterpret_cast<const float4*>(
                x + ((size_t)(row0 + k + 1) << 16));
            #pragma unroll
            for (int i = 0; i < 8; ++i) {
                buf[2 * i]     = src[i * 2048 + t * 2];
                buf[2 * i + 1] = src[i * 2048 + t * 2 + 1];
            }
        }
        __builtin_amdgcn_sched_barrier(0);
        lds_barrier();
    }
}

__global__ void __launch_bounds__(256)
map_kernel_nows(const float* __restrict__ x,
                const float* __restrict__ filters,
                const int*   __restrict__ ind,
                float*       __restrict__ out) {
    size_t o = (size_t)blockIdx.x * 256 + threadIdx.x;
    if (o >= (size_t)BATCH * D_ALL) return;
    unsigned b = (unsigned)(o >> 16);
    unsigned rem = (unsigned)(o & 65535u);
    unsigned m = rem >> 9, r = rem & 511u;
    int idx = ind[r * D_ROW + m];
    out[o] = x[((size_t)b << 16) + idx] * filters[(size_t)r * D_ALL + idx];
}

extern "C" void kernel_launch(void* const* d_in, const int* in_sizes, int n_in,
                              void* d_out, int out_size, void* d_ws, size_t ws_size,
                              hipStream_t stream) {
    const float* x       = (const float*)d_in[0];
    const float* filters = (const float*)d_in[1];
    const int*   ind     = (const int*)d_in[2];
    float*       out     = (float*)d_out;

    // ws layout for map12
    const size_t off_offs = 0;                               // u32[131072]
    const size_t off_part = off_offs + (size_t)NBIN * 4;     // u32[128] (+pad to 512)
    const size_t off_ir   = off_part + 512;                  // u32[65536]
    const size_t off_w    = off_ir + (size_t)D_ALL * 4;      // u16[65536]
    const size_t need12   = off_w + (size_t)D_ALL * 2;       // ~1.0 MB
    const size_t need8    = (size_t)D_ALL * sizeof(unsigned);

    if (ws_size >= need12) {
        unsigned* offs = (unsigned*)((char*)d_ws + off_offs);
        unsigned* part = (unsigned*)((char*)d_ws + off_part);
        unsigned* irb  = (unsigned*)((char*)d_ws + off_ir);
        unsigned short* wbuf = (unsigned short*)((char*)d_ws + off_w);
        k_zero   <<<NBIN / 1024, 1024, 0, stream>>>(offs);
        k_hist   <<<D_ALL / 1024, 1024, 0, stream>>>(ind, offs);
        k_scan1  <<<NBIN / 1024, 1024, 0, stream>>>(offs, part);
        k_scan2  <<<1, 128, 0, stream>>>(part);
        k_scatter<<<D_ALL / 1024, 1024, 0, stream>>>(filters, ind, offs, part, irb, wbuf);
        map12<<<2 * BATCH, 1024, 0, stream>>>(
            x, reinterpret_cast<const uint4*>(irb),
            reinterpret_cast<const ushort4*>(wbuf), out);
    } else if (ws_size >= need8) {
        unsigned* pk = (unsigned*)d_ws;
        build_pk<<<D_ALL / 256, 256, 0, stream>>>(filters, ind, pk);
        map8<<<BATCH / 4, 1024, 0, stream>>>(
            x, reinterpret_cast<const uint4*>(pk), out);
    } else {
        map_kernel_nows<<<(BATCH * (size_t)D_ALL) / 256, 256, 0, stream>>>(
            x, filters, ind, out);
    }
}

// Round 14
// 116.244 us; speedup vs baseline: 1.5342x; 1.4242x over previous
//
#include <hip/hip_runtime.h>
#include <hip/hip_fp16.h>

// out[b, m, r] = x[b, ind[r,m]] * filters[r, ind[r,m]]
// rem = m*512+r; out flat = b*65536 + rem.
//
// map13 = map8 family (LDS-staged x, LDS gathers are cheap) restructured for
// inter-block overlap: ONE row per block, grid=1024 (4 blocks/CU serial).
// When block n is in its store-heavy compute phase / exiting, the CP
// dispatches block n+1 whose stage (HBM reads) overlaps n's store drain --
// read/write overlap across blocks instead of in-kernel prefetch regs.
// Compute uses a 1-ahead pk pipeline (ONE uint4 -- 4 regs, survives the
// allocator unlike R3-R6's 16-64 reg tables) so pk waits don't queue behind
// the output stores issued in the previous group (vmcnt counts stores too).

constexpr int D_ROW = 128;
constexpr int D_COL = 512;
constexpr int D_ALL = D_ROW * D_COL;   // 65536
constexpr int BATCH = 1024;

// pk[m*512+r] = (fp16bits(filters[r, ind[r,m]]) << 16) | ind[r,m]
__global__ void __launch_bounds__(256)
build_pk(const float* __restrict__ filters,
         const int*   __restrict__ ind,
         unsigned* __restrict__ pk) {
    int t = blockIdx.x * 256 + threadIdx.x;
    if (t >= D_ALL) return;
    int m = t >> 9, r = t & 511;
    int idx = ind[r * D_ROW + m];
    __half hw = __float2half_rn(filters[(size_t)r * D_ALL + idx]);
    pk[t] = ((unsigned)__half_as_ushort(hw) << 16) | (unsigned)idx;
}

__device__ __forceinline__ float map_one(const __half* xs, unsigned p) {
    return __half2float(xs[p & 0xffffu]) *
           __half2float(__ushort_as_half((unsigned short)(p >> 16)));
}
__device__ __forceinline__ unsigned h2bits(float a, float b) {
    __half2 h = __floats2half2_rn(a, b);
    return *reinterpret_cast<unsigned*>(&h);
}
__device__ __forceinline__ void lds_barrier() {
    asm volatile("s_waitcnt lgkmcnt(0)" ::: "memory");
    __builtin_amdgcn_s_barrier();
}

__global__ void __launch_bounds__(1024)
map13(const float* __restrict__ x,
      const uint4* __restrict__ pk4,    // pk4[j*1024 + t]
      float* __restrict__ out) {
    __shared__ __half xs[D_ALL];        // 128 KB: full row as fp16
    const int t = threadIdx.x;          // 0..1023
    const int b = blockIdx.x;           // one batch row per block

    // ---- stage: x row -> fp16 LDS. Compiler pipelines the 16 loads across
    // the unrolled body (counted vmcnt); no persistent buf regs needed.
    const float4* src = reinterpret_cast<const float4*>(x + ((size_t)b << 16));
    #pragma unroll
    for (int i = 0; i < 8; ++i) {
        float4 v0 = src[i * 2048 + t * 2];
        float4 v1 = src[i * 2048 + t * 2 + 1];
        uint4 u;
        u.x = h2bits(v0.x, v0.y);
        u.y = h2bits(v0.z, v0.w);
        u.z = h2bits(v1.x, v1.y);
        u.w = h2bits(v1.z, v1.w);
        *reinterpret_cast<uint4*>(xs + (size_t)(i * 2048 + t * 2) * 4) = u;
    }
    lds_barrier();

    // ---- compute: 64 outputs/thread; pk pipelined 1 group ahead so the
    // wait for pk[j+1] is never behind group j's stores in the vmcnt queue.
    float* ob = out + ((size_t)b << 16);
    uint4 p = pk4[t];
    #pragma unroll 4
    for (int j = 0; j < 16; ++j) {
        uint4 cur = p;
        if (j + 1 < 16) p = pk4[(j + 1) * 1024 + t];   // issue before stores
        float4 r;
        r.x = map_one(xs, cur.x);
        r.y = map_one(xs, cur.y);
        r.z = map_one(xs, cur.z);
        r.w = map_one(xs, cur.w);
        *reinterpret_cast<float4*>(ob + j * 4096 + t * 4) = r;
    }
}

// ---------------- fallback: direct gather (correct, slow) ----------------
__global__ void __launch_bounds__(256)
map_kernel_nows(const float* __restrict__ x,
                const float* __restrict__ filters,
                const int*   __restrict__ ind,
                float*       __restrict__ out) {
    size_t o = (size_t)blockIdx.x * 256 + threadIdx.x;
    if (o >= (size_t)BATCH * D_ALL) return;
    unsigned b = (unsigned)(o >> 16);
    unsigned rem = (unsigned)(o & 65535u);
    unsigned m = rem >> 9, r = rem & 511u;
    int idx = ind[r * D_ROW + m];
    out[o] = x[((size_t)b << 16) + idx] * filters[(size_t)r * D_ALL + idx];
}

extern "C" void kernel_launch(void* const* d_in, const int* in_sizes, int n_in,
                              void* d_out, int out_size, void* d_ws, size_t ws_size,
                              hipStream_t stream) {
    const float* x       = (const float*)d_in[0];
    const float* filters = (const float*)d_in[1];
    const int*   ind     = (const int*)d_in[2];
    float*       out     = (float*)d_out;

    const size_t need = (size_t)D_ALL * sizeof(unsigned);   // 256 KB
    if (ws_size >= need) {
        unsigned* pk = (unsigned*)d_ws;
        build_pk<<<D_ALL / 256, 256, 0, stream>>>(filters, ind, pk);
        map13<<<BATCH, 1024, 0, stream>>>(
            x, reinterpret_cast<const uint4*>(pk), out);
    } else {
        map_kernel_nows<<<(BATCH * (size_t)D_ALL) / 256, 256, 0, stream>>>(
            x, filters, ind, out);
    }
}